// Round 7
// baseline (208.533 us; speedup 1.0000x reference)
//
#include <hip/hip_runtime.h>
#include <math.h>

// Problem constants (fixed by reference setup_inputs)
constexpr int Nn = 2, Hh = 8, Ll = 2048, Dd = 64;
constexpr int S  = Nn * Hh;      // 16 sequences
constexpr int C  = 64;           // chunk length
constexpr int NC = Ll / C;       // 32 chunks/seq
constexpr int SC = S * NC;       // 512 chunk-blocks

constexpr int SB  = 72;          // bf16 LDS row stride (144 B rows, 16B-aligned)
constexpr int SRP = 65;          // fp32 score-matrix stride

#define EPSF 1e-6f

typedef __attribute__((ext_vector_type(8))) short short8;
typedef __attribute__((ext_vector_type(4))) float f32x4;
#define MFMA16(a, b, c) __builtin_amdgcn_mfma_f32_16x16x32_bf16(a, b, c, 0, 0, 0)

__device__ __forceinline__ float sigf(float x) { return 1.0f / (1.0f + expf(-x)); }

__device__ __forceinline__ float waveRed(float v) {
#pragma unroll
    for (int off = 32; off > 0; off >>= 1) v += __shfl_xor(v, off, 64);
    return v;
}

__device__ __forceinline__ int gidx(int n, int l, int h, int d) {
    return ((n * Ll + l) * Hh + h) * Dd + d;
}

__device__ __forceinline__ float fc(const float4& v, int u) { return ((const float*)&v)[u]; }

__device__ __forceinline__ unsigned short f2bf(float x) {
    unsigned int u = __float_as_uint(x);
    unsigned int r = (u + 0x7fffu + ((u >> 16) & 1u)) >> 16;   // RNE
    return (unsigned short)r;
}
__device__ __forceinline__ unsigned int pack2(float lo, float hi) {
    return (unsigned int)f2bf(lo) | ((unsigned int)f2bf(hi) << 16);
}
__device__ __forceinline__ float bf2f(unsigned short u) {
    return __uint_as_float(((unsigned int)u) << 16);
}

__device__ __forceinline__ void flagSet(int* p) {
    __hip_atomic_store(p, 1, __ATOMIC_RELEASE, __HIP_MEMORY_SCOPE_AGENT);
}
__device__ __forceinline__ void flagWait(const int* p) {
    while (__hip_atomic_load(p, __ATOMIC_ACQUIRE, __HIP_MEMORY_SCOPE_AGENT) == 0)
        __builtin_amdgcn_s_sleep(1);
}

// ============ Kernel A: sums + pass1 (lookback prefix on SK/SQ) ============
__global__ __launch_bounds__(256) void k_A(const float* __restrict__ Q,
                                           const float* __restrict__ K,
                                           float* __restrict__ SK,
                                           float* __restrict__ SQ,
                                           int* __restrict__ flagA,
                                           float* __restrict__ SKso,
                                           float* __restrict__ SQsi,
                                           float* __restrict__ si_g,
                                           float* __restrict__ rw1_g,
                                           float* __restrict__ rw2_g,
                                           float* __restrict__ Pg) {
    __shared__ __align__(16) unsigned short sqB[C * SB];   // [i][d] bf16
    __shared__ __align__(16) unsigned short skB[C * SB];
    __shared__ float P[C * SRP];      // scratch pre-MFMA, scores post-MFMA
    __shared__ float scrP[512];
    __shared__ float colK[C], colQ[C], pk[Dd], pq[Dd], lsi[C], lso[C];
    int b = blockIdx.x, s = b / NC, c = b % NC;
    int n = s / Hh, h = s % Hh, t = threadIdx.x;

    // stage bf16 + partials (colK/colQ per-i over d-quad; SK/SQ per-d over 4 i's)
    int d0 = (4 * t) & 63, ig = t >> 4;
    float psk[4] = {0, 0, 0, 0}, psq[4] = {0, 0, 0, 0};
#pragma unroll
    for (int j = 0; j < 4; j++) {
        int i = ig + 16 * j;
        int id = gidx(n, c * C + i, h, d0);
        float4 q4 = *(const float4*)&Q[id];
        float4 k4 = *(const float4*)&K[id];
        float sq0 = sigf(q4.x), sq1 = sigf(q4.y), sq2 = sigf(q4.z), sq3 = sigf(q4.w);
        float sk0 = sigf(k4.x), sk1 = sigf(k4.y), sk2 = sigf(k4.z), sk3 = sigf(k4.w);
        *(uint2*)&sqB[i * SB + d0] = make_uint2(pack2(sq0, sq1), pack2(sq2, sq3));
        *(uint2*)&skB[i * SB + d0] = make_uint2(pack2(sk0, sk1), pack2(sk2, sk3));
        P[i * 16 + (t & 15)]        = sk0 + sk1 + sk2 + sk3;   // colK scratch
        P[1024 + i * 16 + (t & 15)] = sq0 + sq1 + sq2 + sq3;   // colQ scratch
        psk[0] += sk0; psk[1] += sk1; psk[2] += sk2; psk[3] += sk3;
        psq[0] += sq0; psq[1] += sq1; psq[2] += sq2; psq[3] += sq3;
    }
#pragma unroll
    for (int r = 0; r < 4; r++) {
        P[2048 + ig * 64 + d0 + r] = psk[r];   // SK scratch
        P[3072 + ig * 64 + d0 + r] = psq[r];   // SQ scratch
    }
    __syncthreads();

    if (t < 64) {
        float v = 0.f;
#pragma unroll
        for (int u = 0; u < 16; u++) v += P[t * 16 + u];
        colK[t] = v;
    } else if (t < 128) {
        int i = t - 64; float v = 0.f;
#pragma unroll
        for (int u = 0; u < 16; u++) v += P[1024 + i * 16 + u];
        colQ[i] = v;
    } else if (t < 192) {
        int d = t - 128; float v = 0.f;
#pragma unroll
        for (int g = 0; g < 16; g++) v += P[2048 + g * 64 + d];
        SK[b * 64 + d] = v;
    } else {
        int d = t - 192; float v = 0.f;
#pragma unroll
        for (int g = 0; g < 16; g++) v += P[3072 + g * 64 + d];
        SQ[b * 64 + d] = v;
    }
    __syncthreads();   // SK/SQ stores drained (vmcnt(0) before barrier)
    if (t == 0) flagSet(&flagA[b]);

    // MFMA: P = sq · sk^T  (independent of prefix — hides lookback latency)
    int w = t >> 6, lane = t & 63, m = lane & 15, q = lane >> 4;
    {
        f32x4 acc[4] = {{0,0,0,0},{0,0,0,0},{0,0,0,0},{0,0,0,0}};
#pragma unroll
        for (int kk = 0; kk < 64; kk += 32) {
            short8 a = *(const short8*)&sqB[(16 * w + m) * SB + kk + q * 8];
#pragma unroll
            for (int J = 0; J < 4; J++) {
                short8 bb = *(const short8*)&skB[(16 * J + m) * SB + kk + q * 8];
                acc[J] = MFMA16(a, bb, acc[J]);
            }
        }
#pragma unroll
        for (int J = 0; J < 4; J++)
#pragma unroll
            for (int r = 0; r < 4; r++) {
                int io = 16 * w + 4 * q + r, jo = 16 * J + m;
                P[io * SRP + jo] = acc[J][r];
                Pg[(size_t)b * 4096 + io * 64 + jo] = acc[J][r];
            }
    }
    // lookback prefix of SK/SQ (4 waves, strided chunks)
    {
        float pa = 0.f, pb = 0.f;
        for (int cp = w; cp < c; cp += 4) {
            flagWait(&flagA[s * NC + cp]);
            pa += SK[(s * NC + cp) * 64 + lane];
            pb += SQ[(s * NC + cp) * 64 + lane];
        }
        scrP[w * 64 + lane] = pa;
        scrP[256 + w * 64 + lane] = pb;
    }
    __syncthreads();
    if (t < 64) pk[t] = scrP[t] + scrP[64 + t] + scrP[128 + t] + scrP[192 + t];
    else if (t < 128) {
        int d = t - 64;
        pq[d] = scrP[256 + d] + scrP[320 + d] + scrP[384 + d] + scrP[448 + d];
    }
    __syncthreads();

    if (t < 64) {
        int i = t, l = c * C + i;
        float r1 = 0.f, r2 = 0.f;
        for (int j = 0; j <= i; j++) {
            r1 += P[i * SRP + j] + EPSF * colK[j];
            r2 += P[j * SRP + i] + EPSF * colQ[j];
        }
        float b1 = 0.f, b2 = 0.f;
        for (int d = 0; d < Dd; d++) {
            b1 += (bf2f(sqB[i * SB + d]) + EPSF) * (pk[d] + EPSF);
            b2 += (bf2f(skB[i * SB + d]) + EPSF) * (pq[d] + EPSF);
        }
        float nf = (float)(l + 1);
        float siF = nf / (b1 + r1), soF = nf / (b2 + r2);
        si_g[s * Ll + l] = siF;
        lsi[i] = siF; lso[i] = soF;
    }
    __syncthreads();

    if (t < 64) {
        int i = t; float v = 0.f;
        for (int j = 0; j <= i; j++) v += lso[j] * (P[i * SRP + j] + EPSF * colK[j]);
        rw1_g[s * Ll + c * C + i] = v;
    } else if (t < 128) {
        int i = t - 64; float v = 0.f;
        for (int j = 0; j <= i; j++) v += lsi[j] * (P[j * SRP + i] + EPSF * colQ[j]);
        rw2_g[s * Ll + c * C + i] = v;
    } else if (t < 192) {
        int d = t - 128; float v = 0.f;
        for (int i = 0; i < C; i++) v += bf2f(skB[i * SB + d]) * lso[i];
        SKso[b * 64 + d] = v;
    } else {
        int d = t - 192; float v = 0.f;
        for (int i = 0; i < C; i++) v += bf2f(sqB[i * SB + d]) * lsi[i];
        SQsi[b * 64 + d] = v;
    }
}

// ============ Kernel B: pass2 + kv (lookback on Tcs) ============
__global__ __launch_bounds__(256) void k_B(const float* __restrict__ Q,
                                           const float* __restrict__ K,
                                           const float* __restrict__ V,
                                           const float* __restrict__ SKso,
                                           const float* __restrict__ SQsi,
                                           const float* __restrict__ si_g,
                                           const float* __restrict__ rw1_g,
                                           const float* __restrict__ rw2_g,
                                           float* __restrict__ s2_g,
                                           float* __restrict__ Tcs,
                                           int* __restrict__ flagB,
                                           float* __restrict__ scomp_g,
                                           float* __restrict__ KVT) {
    __shared__ __align__(16) unsigned short skT[Dd * SB];   // [d][i]
    __shared__ __align__(16) unsigned short vsT[Dd * SB];   // [m][i]
    __shared__ float scr[512];
    __shared__ float pks[Dd], pqs[Dd], le[C], lecum[C], lsc[C];
    __shared__ float pcsv;
    int b = blockIdx.x, s = b / NC, c = b % NC;
    int n = s / Hh, h = s % Hh, t = threadIdx.x;

    {   // parallel prefix of SKso/SQsi (A finished: kernel boundary)
        int d = t & 63, g = t >> 6;
        float pa = 0.f, pb = 0.f;
        for (int cp = g; cp < c; cp += 4) {
            pa += SKso[(s * NC + cp) * 64 + d];
            pb += SQsi[(s * NC + cp) * 64 + d];
        }
        scr[g * 64 + d] = pa;
        scr[256 + g * 64 + d] = pb;
    }
    __syncthreads();
    if (t < 64) pks[t] = scr[t] + scr[64 + t] + scr[128 + t] + scr[192 + t];
    else if (t < 128) {
        int d = t - 64;
        pqs[d] = scr[256 + d] + scr[320 + d] + scr[384 + d] + scr[448 + d];
    }
    __syncthreads();

    {   // b1/b2 matvec: 4 lanes per row
        int i = t >> 2, g = t & 3, l = c * C + i;
        float b1 = 0.f, b2 = 0.f;
#pragma unroll
        for (int u = 0; u < 4; u++) {
            int d = g * 16 + 4 * u;
            float4 q4 = *(const float4*)&Q[gidx(n, l, h, d)];
            float4 k4 = *(const float4*)&K[gidx(n, l, h, d)];
#pragma unroll
            for (int ww = 0; ww < 4; ww++) {
                b1 += (sigf(fc(q4, ww)) + EPSF) * (pks[d + ww] + EPSF);
                b2 += (sigf(fc(k4, ww)) + EPSF) * (pqs[d + ww] + EPSF);
            }
        }
        b1 += __shfl_xor(b1, 1, 64); b1 += __shfl_xor(b1, 2, 64);
        b2 += __shfl_xor(b2, 1, 64); b2 += __shfl_xor(b2, 2, 64);
        if (g == 0) {
            float nf = (float)(l + 1);
            float cs  = (b1 + rw1_g[s * Ll + l]) / nf;
            float csr = (b2 + rw2_g[s * Ll + l]) / nf;
            csr = fminf(fmaxf(csr, -1.f), 1.f);
            float e = expf(csr);
            float sal = 1.0f / (1.0f + expf(-cs));
            s2_g[s * Ll + l] = si_g[s * Ll + l] / nf * sal;
            le[i] = e;
        }
    }
    __syncthreads();
    if (t < 64) {
        float run = le[t];
#pragma unroll
        for (int off = 1; off < 64; off <<= 1) {
            float o = __shfl_up(run, off, 64);
            if (t >= off) run += o;
        }
        lecum[t] = run;
        if (t == 63) {   // publish chunk total (same-thread store→fence→flag ordering)
            Tcs[b] = run;
            flagSet(&flagB[b]);
        }
    }
    __syncthreads();
    if (t < 64) {   // scalar lookback: sum predecessor totals
        float v = 0.f;
        if (t < c) {
            flagWait(&flagB[s * NC + t]);
            v = Tcs[s * NC + t];
        }
        v = waveRed(v);
        if (t == 0) pcsv = v;
    }
    __syncthreads();
    if (t < 64) {
        int l = c * C + t;
        float ls = le[t] / (pcsv + lecum[t]) * (float)(l + 1);
        lsc[t] = ls;
        scomp_g[s * Ll + l] = ls;
    }
    __syncthreads();

    {   // transposed staging of k, v*scomp
        int i0 = (t & 15) * 4, d0 = (((t >> 4) & 3) + 4 * (t >> 6)) * 4;
        float4 kr[4], vr[4];
#pragma unroll
        for (int r = 0; r < 4; r++) {
            int id = gidx(n, c * C + i0 + r, h, d0);
            kr[r] = *(const float4*)&K[id];
            vr[r] = *(const float4*)&V[id];
        }
        float sc0 = lsc[i0], sc1 = lsc[i0 + 1], sc2 = lsc[i0 + 2], sc3 = lsc[i0 + 3];
#pragma unroll
        for (int u = 0; u < 4; u++) {
            *(uint2*)&skT[(d0 + u) * SB + i0] = make_uint2(
                pack2(sigf(fc(kr[0], u)), sigf(fc(kr[1], u))),
                pack2(sigf(fc(kr[2], u)), sigf(fc(kr[3], u))));
            *(uint2*)&vsT[(d0 + u) * SB + i0] = make_uint2(
                pack2(fc(vr[0], u) * sc0, fc(vr[1], u) * sc1),
                pack2(fc(vr[2], u) * sc2, fc(vr[3], u) * sc3));
        }
    }
    __syncthreads();

    {   // MFMA: KVT[m][d] = sum_i vsT[m][i] * skT[d][i]
        int w = t >> 6, lane = t & 63, m = lane & 15, q = lane >> 4;
        f32x4 acc[4] = {{0,0,0,0},{0,0,0,0},{0,0,0,0},{0,0,0,0}};
#pragma unroll
        for (int kk = 0; kk < 64; kk += 32) {
            short8 a = *(const short8*)&vsT[(16 * w + m) * SB + kk + q * 8];
#pragma unroll
            for (int J = 0; J < 4; J++) {
                short8 bb = *(const short8*)&skT[(16 * J + m) * SB + kk + q * 8];
                acc[J] = MFMA16(a, bb, acc[J]);
            }
        }
#pragma unroll
        for (int J = 0; J < 4; J++)
#pragma unroll
            for (int r = 0; r < 4; r++)
                KVT[(size_t)b * 4096 + (16 * w + 4 * q + r) * 64 + 16 * J + m] = acc[J][r];
    }
}

// ============ Kernel C: final (KV lookback-sum, no prefix kernel) ============
__global__ __launch_bounds__(256) void k_C(const float* __restrict__ Q,
                                           const float* __restrict__ V,
                                           const float* __restrict__ s2_g,
                                           const float* __restrict__ scomp_g,
                                           const float* __restrict__ Pg,
                                           const float* __restrict__ KVT,
                                           float* __restrict__ Out) {
    __shared__ __align__(16) unsigned short sqB[C * SB];    // [i][d]
    __shared__ __align__(16) unsigned short kvB[C * SB];    // [m][d] = prefix-KV rows
    __shared__ __align__(16) unsigned short stB[C * SB];    // [i][j] masked P*scomp
    __shared__ __align__(16) unsigned short vsT[C * SB];    // [m][j]
    __shared__ float lsc[C], s2l[C];
    int b = blockIdx.x, s = b / NC, c = b % NC;
    int n = s / Hh, h = s % Hh, t = threadIdx.x;

    if (t < 64) lsc[t] = scomp_g[s * Ll + c * C + t];
    else if (t < 128) s2l[t - 64] = s2_g[s * Ll + c * C + (t - 64)];

    // KV prefix via direct sum of predecessor chunk-KVs (L2/L3-resident)
    {
        float4 acc4[4] = {{0,0,0,0},{0,0,0,0},{0,0,0,0},{0,0,0,0}};
        for (int cp = 0; cp < c; cp++) {
            const float* src = &KVT[(size_t)(s * NC + cp) * 4096];
#pragma unroll
            for (int j = 0; j < 4; j++) {
                float4 x = *(const float4*)&src[4 * t + 1024 * j];
                acc4[j].x += x.x; acc4[j].y += x.y; acc4[j].z += x.z; acc4[j].w += x.w;
            }
        }
#pragma unroll
        for (int j = 0; j < 4; j++) {
            int flat = 4 * t + 1024 * j, i = flat >> 6, d0 = flat & 63;
            *(uint2*)&kvB[i * SB + d0] = make_uint2(pack2(acc4[j].x, acc4[j].y),
                                                    pack2(acc4[j].z, acc4[j].w));
        }
    }
    __syncthreads();   // lsc ready before stB masking below

    // natural-row staging: sq, masked-P
#pragma unroll
    for (int j = 0; j < 4; j++) {
        int flat = 4 * t + 1024 * j, i = flat >> 6, d0 = flat & 63;
        float4 q4 = *(const float4*)&Q[gidx(n, c * C + i, h, d0)];
        float4 p4 = *(const float4*)&Pg[(size_t)b * 4096 + flat];
        *(uint2*)&sqB[i * SB + d0] = make_uint2(pack2(sigf(q4.x), sigf(q4.y)),
                                                pack2(sigf(q4.z), sigf(q4.w)));
        float m0v = (d0 + 0 <= i) ? fc(p4, 0) * lsc[d0 + 0] : 0.f;
        float m1v = (d0 + 1 <= i) ? fc(p4, 1) * lsc[d0 + 1] : 0.f;
        float m2v = (d0 + 2 <= i) ? fc(p4, 2) * lsc[d0 + 2] : 0.f;
        float m3v = (d0 + 3 <= i) ? fc(p4, 3) * lsc[d0 + 3] : 0.f;
        *(uint2*)&stB[i * SB + d0] = make_uint2(pack2(m0v, m1v), pack2(m2v, m3v));
    }
    // transposed staging of v
    {
        int j0 = (t & 15) * 4, m0 = (((t >> 4) & 3) + 4 * (t >> 6)) * 4;
        float4 vr[4];
#pragma unroll
        for (int r = 0; r < 4; r++) vr[r] = *(const float4*)&V[gidx(n, c * C + j0 + r, h, m0)];
#pragma unroll
        for (int u = 0; u < 4; u++)
            *(uint2*)&vsT[(m0 + u) * SB + j0] = make_uint2(
                pack2(fc(vr[0], u), fc(vr[1], u)), pack2(fc(vr[2], u), fc(vr[3], u)));
    }
    __syncthreads();

    int w = t >> 6, lane = t & 63, m = lane & 15, q = lane >> 4;
    f32x4 acc[4] = {{0,0,0,0},{0,0,0,0},{0,0,0,0},{0,0,0,0}};
#pragma unroll
    for (int kk = 0; kk < 64; kk += 32) {   // mm1: sq · KVp
        short8 a = *(const short8*)&sqB[(16 * w + m) * SB + kk + q * 8];
#pragma unroll
        for (int J = 0; J < 4; J++) {
            short8 bb = *(const short8*)&kvB[(16 * J + m) * SB + kk + q * 8];
            acc[J] = MFMA16(a, bb, acc[J]);
        }
    }
#pragma unroll
    for (int kk = 0; kk < 64; kk += 32) {   // mm2: maskedP·scomp · v
        short8 a = *(const short8*)&stB[(16 * w + m) * SB + kk + q * 8];
#pragma unroll
        for (int J = 0; J < 4; J++) {
            short8 bb = *(const short8*)&vsT[(16 * J + m) * SB + kk + q * 8];
            acc[J] = MFMA16(a, bb, acc[J]);
        }
    }
#pragma unroll
    for (int J = 0; J < 4; J++)
#pragma unroll
        for (int r = 0; r < 4; r++) {
            int io = 16 * w + 4 * q + r;
            Out[gidx(n, c * C + io, h, 16 * J + m)] = acc[J][r] * s2l[io];
        }
}

extern "C" void kernel_launch(void* const* d_in, const int* in_sizes, int n_in,
                              void* d_out, int out_size, void* d_ws, size_t ws_size,
                              hipStream_t stream) {
    const float* Q = (const float*)d_in[0];
    const float* K = (const float*)d_in[1];
    const float* V = (const float*)d_in[2];
    float* Out = (float*)d_out;

    int*   flagA = (int*)d_ws;          // SC
    int*   flagB = flagA + SC;          // SC
    float* ws    = (float*)d_ws + 2 * SC;
    float* SK    = ws;                  // SC*64
    float* SQ    = SK    + SC * 64;
    float* SKso  = SQ    + SC * 64;
    float* SQsi  = SKso  + SC * 64;
    float* si_g  = SQsi  + SC * 64;     // S*Ll each
    float* rw1_g = si_g  + S * Ll;
    float* rw2_g = rw1_g + S * Ll;
    float* s2_g  = rw2_g + S * Ll;
    float* scomp = s2_g  + S * Ll;
    float* Tcs   = scomp + S * Ll;      // SC
    float* Pg    = Tcs   + SC;          // SC*4096
    float* KVT   = Pg    + (size_t)SC * 4096;

    hipMemsetAsync(flagA, 0, 2 * SC * sizeof(int), stream);
    k_A<<<SC, 256, 0, stream>>>(Q, K, SK, SQ, flagA, SKso, SQsi, si_g, rw1_g, rw2_g, Pg);
    k_B<<<SC, 256, 0, stream>>>(Q, K, V, SKso, SQsi, si_g, rw1_g, rw2_g, s2_g, Tcs, flagB, scomp, KVT);
    k_C<<<SC, 256, 0, stream>>>(Q, V, s2_g, scomp, Pg, KVT, Out);
}

// Round 8
// 120.620 us; speedup vs baseline: 1.7288x; 1.7288x over previous
//
#include <hip/hip_runtime.h>
#include <math.h>

// Problem constants (fixed by reference setup_inputs)
constexpr int Nn = 2, Hh = 8, Ll = 2048, Dd = 64;
constexpr int S  = Nn * Hh;      // 16 sequences
constexpr int C  = 64;           // chunk length
constexpr int NC = Ll / C;       // 32 chunks/seq
constexpr int SC = S * NC;       // 512 chunk-blocks

constexpr int SB  = 72;          // bf16 LDS row stride (144 B rows, 16B-aligned)
constexpr int SRP = 65;          // fp32 score-matrix stride

#define EPSF 1e-6f

typedef __attribute__((ext_vector_type(8))) short short8;
typedef __attribute__((ext_vector_type(4))) float f32x4;
#define MFMA16(a, b, c) __builtin_amdgcn_mfma_f32_16x16x32_bf16(a, b, c, 0, 0, 0)

__device__ __forceinline__ float sigf(float x) { return 1.0f / (1.0f + expf(-x)); }

__device__ __forceinline__ float waveRed(float v) {
#pragma unroll
    for (int off = 32; off > 0; off >>= 1) v += __shfl_xor(v, off, 64);
    return v;
}

__device__ __forceinline__ int gidx(int n, int l, int h, int d) {
    return ((n * Ll + l) * Hh + h) * Dd + d;
}

__device__ __forceinline__ float fc(const float4& v, int u) { return ((const float*)&v)[u]; }

__device__ __forceinline__ unsigned short f2bf(float x) {
    unsigned int u = __float_as_uint(x);
    unsigned int r = (u + 0x7fffu + ((u >> 16) & 1u)) >> 16;   // RNE
    return (unsigned short)r;
}
__device__ __forceinline__ unsigned int pack2(float lo, float hi) {
    return (unsigned int)f2bf(lo) | ((unsigned int)f2bf(hi) << 16);
}
__device__ __forceinline__ float bf2f(unsigned short u) {
    return __uint_as_float(((unsigned int)u) << 16);
}

// K1: per-chunk sums of sigmoid(k), sigmoid(q).
__global__ __launch_bounds__(256) void k_sums(const float* __restrict__ Q,
                                              const float* __restrict__ K,
                                              float* __restrict__ SK, float* __restrict__ SQ) {
    __shared__ float scr[2048];
    int b = blockIdx.x, s = b / NC, c = b % NC;
    int n = s / Hh, h = s % Hh, t = threadIdx.x;
    int d0 = (4 * t) & 63, ig = t >> 4;
    float psk[4] = {0, 0, 0, 0}, psq[4] = {0, 0, 0, 0};
#pragma unroll
    for (int j = 0; j < 4; j++) {
        int i = ig + 16 * j;
        int id = gidx(n, c * C + i, h, d0);
        float4 q4 = *(const float4*)&Q[id];
        float4 k4 = *(const float4*)&K[id];
        psq[0] += sigf(q4.x); psq[1] += sigf(q4.y); psq[2] += sigf(q4.z); psq[3] += sigf(q4.w);
        psk[0] += sigf(k4.x); psk[1] += sigf(k4.y); psk[2] += sigf(k4.z); psk[3] += sigf(k4.w);
    }
#pragma unroll
    for (int r = 0; r < 4; r++) {
        scr[ig * 64 + d0 + r] = psk[r];
        scr[1024 + ig * 64 + d0 + r] = psq[r];
    }
    __syncthreads();
    if (t < 64) {
        float v = 0.f;
        for (int g = 0; g < 16; g++) v += scr[g * 64 + t];
        SK[b * 64 + t] = v;
    } else if (t < 128) {
        int d = t - 64; float v = 0.f;
        for (int g = 0; g < 16; g++) v += scr[1024 + g * 64 + d];
        SQ[b * 64 + d] = v;
    }
}

// K2: pass1 — stage bf16, MFMA P (->LDS fp32 + Pg), si/so, rw1/rw2, SKso/SQsi.
__global__ __launch_bounds__(256) void k_pass1(const float* __restrict__ Q,
                                               const float* __restrict__ K,
                                               const float* __restrict__ SK,
                                               const float* __restrict__ SQ,
                                               float* __restrict__ SKso,
                                               float* __restrict__ SQsi,
                                               float* __restrict__ si_g,
                                               float* __restrict__ rw1_g,
                                               float* __restrict__ rw2_g,
                                               float* __restrict__ Pg) {
    __shared__ __align__(16) unsigned short sqB[C * SB];   // [i][d] bf16
    __shared__ __align__(16) unsigned short skB[C * SB];
    __shared__ float P[C * SRP];      // fp32; low 2560 doubles as scratch pre-matmul
    __shared__ float colK[C], colQ[C], pk[Dd], pq[Dd], lsi[C], lso[C];
    int b = blockIdx.x, s = b / NC, c = b % NC;
    int n = s / Hh, h = s % Hh, t = threadIdx.x;

    // stage (natural row-major bf16) + per-thread row-sum partials
#pragma unroll
    for (int j = 0; j < 4; j++) {
        int flat = 4 * t + 1024 * j, i = flat >> 6, d0 = flat & 63;
        int id = gidx(n, c * C + i, h, d0);
        float4 q4 = *(const float4*)&Q[id];
        float4 k4 = *(const float4*)&K[id];
        float sq0 = sigf(q4.x), sq1 = sigf(q4.y), sq2 = sigf(q4.z), sq3 = sigf(q4.w);
        float sk0 = sigf(k4.x), sk1 = sigf(k4.y), sk2 = sigf(k4.z), sk3 = sigf(k4.w);
        *(uint2*)&sqB[i * SB + d0] = make_uint2(pack2(sq0, sq1), pack2(sq2, sq3));
        *(uint2*)&skB[i * SB + d0] = make_uint2(pack2(sk0, sk1), pack2(sk2, sk3));
        P[i * 16 + (t & 15)]        = sk0 + sk1 + sk2 + sk3;   // scrColK
        P[1024 + i * 16 + (t & 15)] = sq0 + sq1 + sq2 + sq3;   // scrColQ
    }
    {   // cross-chunk prefix partials (4 groups)
        int d = t & 63, g = t >> 6;
        float pa = 0.f, pb = 0.f;
        for (int cp = g; cp < c; cp += 4) {
            pa += SK[(s * NC + cp) * 64 + d];
            pb += SQ[(s * NC + cp) * 64 + d];
        }
        P[2048 + g * 64 + d] = pa;
        P[2304 + g * 64 + d] = pb;
    }
    __syncthreads();
    if (t < 64) {
        float v = 0.f;
#pragma unroll
        for (int u = 0; u < 16; u++) v += P[t * 16 + u];
        colK[t] = v;
    } else if (t < 128) {
        int i = t - 64; float v = 0.f;
#pragma unroll
        for (int u = 0; u < 16; u++) v += P[1024 + i * 16 + u];
        colQ[i] = v;
    } else if (t < 192) {
        int d = t - 128;
        pk[d] = P[2048 + d] + P[2048 + 64 + d] + P[2048 + 128 + d] + P[2048 + 192 + d];
    } else {
        int d = t - 192;
        pq[d] = P[2304 + d] + P[2304 + 64 + d] + P[2304 + 128 + d] + P[2304 + 192 + d];
    }
    __syncthreads();

    // MFMA: P = sq · sk^T  (wave w = row-block)
    {
        int w = t >> 6, lane = t & 63, m = lane & 15, q = lane >> 4;
        f32x4 acc[4] = {{0,0,0,0},{0,0,0,0},{0,0,0,0},{0,0,0,0}};
#pragma unroll
        for (int kk = 0; kk < 64; kk += 32) {
            short8 a = *(const short8*)&sqB[(16 * w + m) * SB + kk + q * 8];
#pragma unroll
            for (int J = 0; J < 4; J++) {
                short8 bb = *(const short8*)&skB[(16 * J + m) * SB + kk + q * 8];
                acc[J] = MFMA16(a, bb, acc[J]);
            }
        }
#pragma unroll
        for (int J = 0; J < 4; J++)
#pragma unroll
            for (int r = 0; r < 4; r++) {
                int io = 16 * w + 4 * q + r, jo = 16 * J + m;
                P[io * SRP + jo] = acc[J][r];
                Pg[(size_t)b * 4096 + io * 64 + jo] = acc[J][r];
            }
    }
    __syncthreads();

    // si/so  (b1/b2 dots read bf16 rows)
    if (t < 64) {
        int i = t, l = c * C + i;
        float r1 = 0.f, r2 = 0.f;
        for (int j = 0; j <= i; j++) {
            r1 += P[i * SRP + j] + EPSF * colK[j];
            r2 += P[j * SRP + i] + EPSF * colQ[j];
        }
        float b1 = 0.f, b2 = 0.f;
        for (int d = 0; d < Dd; d++) {
            b1 += (bf2f(sqB[i * SB + d]) + EPSF) * (pk[d] + EPSF);
            b2 += (bf2f(skB[i * SB + d]) + EPSF) * (pq[d] + EPSF);
        }
        float nf = (float)(l + 1);
        float siF = nf / (b1 + r1), soF = nf / (b2 + r2);
        si_g[s * Ll + l] = siF;
        lsi[i] = siF; lso[i] = soF;
    }
    __syncthreads();

    // rw1/rw2 + SKso/SQsi (4 groups)
    if (t < 64) {
        int i = t; float v = 0.f;
        for (int j = 0; j <= i; j++) v += lso[j] * (P[i * SRP + j] + EPSF * colK[j]);
        rw1_g[s * Ll + c * C + i] = v;
    } else if (t < 128) {
        int i = t - 64; float v = 0.f;
        for (int j = 0; j <= i; j++) v += lsi[j] * (P[j * SRP + i] + EPSF * colQ[j]);
        rw2_g[s * Ll + c * C + i] = v;
    } else if (t < 192) {
        int d = t - 128; float v = 0.f;
        for (int i = 0; i < C; i++) v += bf2f(skB[i * SB + d]) * lso[i];
        SKso[b * 64 + d] = v;
    } else {
        int d = t - 192; float v = 0.f;
        for (int i = 0; i < C; i++) v += bf2f(sqB[i * SB + d]) * lsi[i];
        SQsi[b * 64 + d] = v;
    }
}

// K3: light pass2 — prefix + direct matvec.
__global__ __launch_bounds__(256) void k_pass2(const float* __restrict__ Q,
                                               const float* __restrict__ K,
                                               const float* __restrict__ SKso,
                                               const float* __restrict__ SQsi,
                                               const float* __restrict__ si_g,
                                               const float* __restrict__ rw1_g,
                                               const float* __restrict__ rw2_g,
                                               float* __restrict__ s2_g,
                                               float* __restrict__ e_g,
                                               float* __restrict__ ecum_g,
                                               float* __restrict__ Tcs) {
    __shared__ float scr[512];
    __shared__ float pks[Dd], pqs[Dd], le[C];
    int b = blockIdx.x, s = b / NC, c = b % NC;
    int n = s / Hh, h = s % Hh, t = threadIdx.x;

    {
        int d = t & 63, g = t >> 6;
        float pa = 0.f, pb = 0.f;
        for (int cp = g; cp < c; cp += 4) {
            pa += SKso[(s * NC + cp) * 64 + d];
            pb += SQsi[(s * NC + cp) * 64 + d];
        }
        scr[g * 64 + d] = pa;
        scr[256 + g * 64 + d] = pb;
    }
    __syncthreads();
    if (t < 64) pks[t] = scr[t] + scr[64 + t] + scr[128 + t] + scr[192 + t];
    else if (t < 128) {
        int d = t - 64;
        pqs[d] = scr[256 + d] + scr[320 + d] + scr[384 + d] + scr[448 + d];
    }
    __syncthreads();

    int i = t >> 2, g = t & 3, l = c * C + i;
    float b1 = 0.f, b2 = 0.f;
#pragma unroll
    for (int u = 0; u < 4; u++) {
        int d = g * 16 + 4 * u;
        float4 q4 = *(const float4*)&Q[gidx(n, l, h, d)];
        float4 k4 = *(const float4*)&K[gidx(n, l, h, d)];
#pragma unroll
        for (int w = 0; w < 4; w++) {
            b1 += (sigf(fc(q4, w)) + EPSF) * (pks[d + w] + EPSF);
            b2 += (sigf(fc(k4, w)) + EPSF) * (pqs[d + w] + EPSF);
        }
    }
    b1 += __shfl_xor(b1, 1, 64); b1 += __shfl_xor(b1, 2, 64);
    b2 += __shfl_xor(b2, 1, 64); b2 += __shfl_xor(b2, 2, 64);
    if (g == 0) {
        float nf = (float)(l + 1);
        float cs  = (b1 + rw1_g[s * Ll + l]) / nf;
        float csr = (b2 + rw2_g[s * Ll + l]) / nf;
        csr = fminf(fmaxf(csr, -1.f), 1.f);
        float e = expf(csr);
        float sal = 1.0f / (1.0f + expf(-cs));
        s2_g[s * Ll + l] = si_g[s * Ll + l] / nf * sal;
        e_g[s * Ll + l] = e;
        le[i] = e;
    }
    __syncthreads();
    if (t < 64) {
        float run = le[t];
#pragma unroll
        for (int off = 1; off < 64; off <<= 1) {
            float o = __shfl_up(run, off, 64);
            if (t >= off) run += o;
        }
        ecum_g[s * Ll + c * C + t] = run;
        if (t == 63) Tcs[b] = run;
    }
}

// K4: scomp + MFMA chunk KV^T[m][d].
__global__ __launch_bounds__(256) void k_kv(const float* __restrict__ K,
                                            const float* __restrict__ V,
                                            const float* __restrict__ e_g,
                                            const float* __restrict__ ecum_g,
                                            const float* __restrict__ Tcs,
                                            float* __restrict__ scomp_g,
                                            float* __restrict__ KVT) {
    __shared__ __align__(16) unsigned short skT[Dd * SB];   // [d][i]
    __shared__ __align__(16) unsigned short vsT[Dd * SB];   // [m][i]
    __shared__ float lsc[C];
    __shared__ float pcsv;
    int b = blockIdx.x, s = b / NC, c = b % NC;
    int n = s / Hh, h = s % Hh, t = threadIdx.x;
    if (t < 64) {
        float v = (t < c) ? Tcs[s * NC + t] : 0.f;
        v = waveRed(v);
        if (t == 0) pcsv = v;
    }
    __syncthreads();
    if (t < 64) {
        int l = c * C + t;
        float ls = e_g[s * Ll + l] / (pcsv + ecum_g[s * Ll + l]) * (float)(l + 1);
        lsc[t] = ls;
        scomp_g[s * Ll + l] = ls;
    }
    __syncthreads();

    {   // transposed staging
        int i0 = (t & 15) * 4, d0 = (((t >> 4) & 3) + 4 * (t >> 6)) * 4;
        float4 kr[4], vr[4];
#pragma unroll
        for (int r = 0; r < 4; r++) {
            int id = gidx(n, c * C + i0 + r, h, d0);
            kr[r] = *(const float4*)&K[id];
            vr[r] = *(const float4*)&V[id];
        }
        float sc0 = lsc[i0], sc1 = lsc[i0 + 1], sc2 = lsc[i0 + 2], sc3 = lsc[i0 + 3];
#pragma unroll
        for (int u = 0; u < 4; u++) {
            *(uint2*)&skT[(d0 + u) * SB + i0] = make_uint2(
                pack2(sigf(fc(kr[0], u)), sigf(fc(kr[1], u))),
                pack2(sigf(fc(kr[2], u)), sigf(fc(kr[3], u))));
            *(uint2*)&vsT[(d0 + u) * SB + i0] = make_uint2(
                pack2(fc(vr[0], u) * sc0, fc(vr[1], u) * sc1),
                pack2(fc(vr[2], u) * sc2, fc(vr[3], u) * sc3));
        }
    }
    __syncthreads();

    {   // MFMA: KVT[m][d] = sum_i vsT[m][i] * skT[d][i]
        int w = t >> 6, lane = t & 63, m = lane & 15, q = lane >> 4;
        f32x4 acc[4] = {{0,0,0,0},{0,0,0,0},{0,0,0,0},{0,0,0,0}};
#pragma unroll
        for (int kk = 0; kk < 64; kk += 32) {
            short8 a = *(const short8*)&vsT[(16 * w + m) * SB + kk + q * 8];
#pragma unroll
            for (int J = 0; J < 4; J++) {
                short8 bb = *(const short8*)&skT[(16 * J + m) * SB + kk + q * 8];
                acc[J] = MFMA16(a, bb, acc[J]);
            }
        }
#pragma unroll
        for (int J = 0; J < 4; J++)
#pragma unroll
            for (int r = 0; r < 4; r++)
                KVT[(size_t)b * 4096 + (16 * w + 4 * q + r) * 64 + 16 * J + m] = acc[J][r];
    }
}

// K5: final — inline KV-prefix sum (flag-free; kernel boundary guarantees KVT ready)
//     + MFMA: out = s2 * ( sq·KVp + maskedP·scomp · v ).
__global__ __launch_bounds__(256) void k_final(const float* __restrict__ Q,
                                               const float* __restrict__ V,
                                               const float* __restrict__ s2_g,
                                               const float* __restrict__ scomp_g,
                                               const float* __restrict__ Pg,
                                               const float* __restrict__ KVT,
                                               float* __restrict__ Out) {
    __shared__ __align__(16) unsigned short sqB[C * SB];    // [i][d]
    __shared__ __align__(16) unsigned short kvB[C * SB];    // [m][d] prefix-KV rows
    __shared__ __align__(16) unsigned short stB[C * SB];    // [i][j] masked P*scomp
    __shared__ __align__(16) unsigned short vsT[C * SB];    // [m][j]
    __shared__ float lsc[C], s2l[C];
    int b = blockIdx.x, s = b / NC, c = b % NC;
    int n = s / Hh, h = s % Hh, t = threadIdx.x;

    if (t < 64) lsc[t] = scomp_g[s * Ll + c * C + t];
    else if (t < 128) s2l[t - 64] = s2_g[s * Ll + c * C + (t - 64)];

    // KV prefix via direct sum of predecessor chunk-KVs (L2/L3-resident)
    {
        float4 acc4[4] = {{0,0,0,0},{0,0,0,0},{0,0,0,0},{0,0,0,0}};
        for (int cp = 0; cp < c; cp++) {
            const float* src = &KVT[(size_t)(s * NC + cp) * 4096];
#pragma unroll
            for (int j = 0; j < 4; j++) {
                float4 x = *(const float4*)&src[4 * t + 1024 * j];
                acc4[j].x += x.x; acc4[j].y += x.y; acc4[j].z += x.z; acc4[j].w += x.w;
            }
        }
#pragma unroll
        for (int j = 0; j < 4; j++) {
            int flat = 4 * t + 1024 * j, i = flat >> 6, d0 = flat & 63;
            *(uint2*)&kvB[i * SB + d0] = make_uint2(pack2(acc4[j].x, acc4[j].y),
                                                    pack2(acc4[j].z, acc4[j].w));
        }
    }
    __syncthreads();   // lsc ready before stB masking

    // natural-row staging: sq, masked-P
#pragma unroll
    for (int j = 0; j < 4; j++) {
        int flat = 4 * t + 1024 * j, i = flat >> 6, d0 = flat & 63;
        float4 q4 = *(const float4*)&Q[gidx(n, c * C + i, h, d0)];
        float4 p4 = *(const float4*)&Pg[(size_t)b * 4096 + flat];
        *(uint2*)&sqB[i * SB + d0] = make_uint2(pack2(sigf(q4.x), sigf(q4.y)),
                                                pack2(sigf(q4.z), sigf(q4.w)));
        float m0v = (d0 + 0 <= i) ? fc(p4, 0) * lsc[d0 + 0] : 0.f;
        float m1v = (d0 + 1 <= i) ? fc(p4, 1) * lsc[d0 + 1] : 0.f;
        float m2v = (d0 + 2 <= i) ? fc(p4, 2) * lsc[d0 + 2] : 0.f;
        float m3v = (d0 + 3 <= i) ? fc(p4, 3) * lsc[d0 + 3] : 0.f;
        *(uint2*)&stB[i * SB + d0] = make_uint2(pack2(m0v, m1v), pack2(m2v, m3v));
    }
    // transposed staging of v
    {
        int j0 = (t & 15) * 4, m0 = (((t >> 4) & 3) + 4 * (t >> 6)) * 4;
        float4 vr[4];
#pragma unroll
        for (int r = 0; r < 4; r++) vr[r] = *(const float4*)&V[gidx(n, c * C + j0 + r, h, m0)];
#pragma unroll
        for (int u = 0; u < 4; u++)
            *(uint2*)&vsT[(m0 + u) * SB + j0] = make_uint2(
                pack2(fc(vr[0], u), fc(vr[1], u)), pack2(fc(vr[2], u), fc(vr[3], u)));
    }
    __syncthreads();

    int w = t >> 6, lane = t & 63, m = lane & 15, q = lane >> 4;
    f32x4 acc[4] = {{0,0,0,0},{0,0,0,0},{0,0,0,0},{0,0,0,0}};
#pragma unroll
    for (int kk = 0; kk < 64; kk += 32) {   // mm1: sq · KVp
        short8 a = *(const short8*)&sqB[(16 * w + m) * SB + kk + q * 8];
#pragma unroll
        for (int J = 0; J < 4; J++) {
            short8 bb = *(const short8*)&kvB[(16 * J + m) * SB + kk + q * 8];
            acc[J] = MFMA16(a, bb, acc[J]);
        }
    }
#pragma unroll
    for (int kk = 0; kk < 64; kk += 32) {   // mm2: maskedP·scomp · v
        short8 a = *(const short8*)&stB[(16 * w + m) * SB + kk + q * 8];
#pragma unroll
        for (int J = 0; J < 4; J++) {
            short8 bb = *(const short8*)&vsT[(16 * J + m) * SB + kk + q * 8];
            acc[J] = MFMA16(a, bb, acc[J]);
        }
    }
#pragma unroll
    for (int J = 0; J < 4; J++)
#pragma unroll
        for (int r = 0; r < 4; r++) {
            int io = 16 * w + 4 * q + r;
            Out[gidx(n, c * C + io, h, 16 * J + m)] = acc[J][r] * s2l[io];
        }
}

extern "C" void kernel_launch(void* const* d_in, const int* in_sizes, int n_in,
                              void* d_out, int out_size, void* d_ws, size_t ws_size,
                              hipStream_t stream) {
    const float* Q = (const float*)d_in[0];
    const float* K = (const float*)d_in[1];
    const float* V = (const float*)d_in[2];
    float* Out = (float*)d_out;

    float* ws    = (float*)d_ws;
    float* SK    = ws;                  // SC*64
    float* SQ    = SK    + SC * 64;
    float* SKso  = SQ    + SC * 64;
    float* SQsi  = SKso  + SC * 64;
    float* si_g  = SQsi  + SC * 64;     // S*Ll each
    float* rw1_g = si_g  + S * Ll;
    float* rw2_g = rw1_g + S * Ll;
    float* s2_g  = rw2_g + S * Ll;
    float* e_g   = s2_g  + S * Ll;
    float* ecum_g= e_g   + S * Ll;
    float* scomp = ecum_g+ S * Ll;
    float* Tcs   = scomp + S * Ll;      // SC
    float* Pg    = Tcs   + SC;          // SC*4096
    float* KVT   = Pg    + (size_t)SC * 4096;

    k_sums<<<SC, 256, 0, stream>>>(Q, K, SK, SQ);
    k_pass1<<<SC, 256, 0, stream>>>(Q, K, SK, SQ, SKso, SQsi, si_g, rw1_g, rw2_g, Pg);
    k_pass2<<<SC, 256, 0, stream>>>(Q, K, SKso, SQsi, si_g, rw1_g, rw2_g, s2_g, e_g, ecum_g, Tcs);
    k_kv<<<SC, 256, 0, stream>>>(K, V, e_g, ecum_g, Tcs, scomp, KVT);
    k_final<<<SC, 256, 0, stream>>>(Q, V, s2_g, scomp, Pg, KVT, Out);
}